// Round 4
// baseline (1012.503 us; speedup 1.0000x reference)
//
#include <hip/hip_runtime.h>
#include <hip/hip_fp16.h>
#include <math.h>

#define D 128

typedef float f4v __attribute__((ext_vector_type(4)));

__device__ __forceinline__ float sigmoidf_(float x) { return 1.f / (1.f + __expf(-x)); }

__device__ __forceinline__ float4 pack8_to_half8(const float* xf) {
    __half2 hh[4];
    hh[0] = __floats2half2_rn(xf[0], xf[1]);
    hh[1] = __floats2half2_rn(xf[2], xf[3]);
    hh[2] = __floats2half2_rn(xf[4], xf[5]);
    hh[3] = __floats2half2_rn(xf[6], xf[7]);
    return *(float4*)hh;
}

// ---------------- prep: WcatT | seg_off | b_sum,h1,c1 ----------------
// WcatT[k][j] (k<256 input dim, j<512 gate rows), layout [256][512]:
//   k<128 : W_ih[j][k] + W_hh[j][k]   (h part)
//   k>=128: W_ih[j][k]                (r part)
__global__ void prep_kernel(const float* __restrict__ W_ih, const float* __restrict__ W_hh,
                            const float* __restrict__ b_ih, const float* __restrict__ b_hh,
                            const int* __restrict__ idx, int N, int G,
                            float* __restrict__ WcatT, int* __restrict__ seg_off,
                            float* __restrict__ b_sum, float* __restrict__ h1,
                            float* __restrict__ c1) {
    int b = blockIdx.x, t = threadIdx.x;
    if (b < 256) {
        int k = b;
        for (int j = t; j < 512; j += 256) {
            float v = W_ih[(size_t)j * 256 + k];
            if (k < 128) v += W_hh[(size_t)j * 128 + k];
            WcatT[(size_t)k * 512 + j] = v;
        }
    } else if (b < 273) {
        int g = (b - 256) * 256 + t;
        if (g <= G) {
            int lo = 0, hi = N;
            while (lo < hi) {
                int mid = (lo + hi) >> 1;
                if (idx[mid] < g) lo = mid + 1; else hi = mid;
            }
            seg_off[g] = lo;
        }
    } else {
        for (int i = t; i < 4 * D; i += 256) b_sum[i] = b_ih[i] + b_hh[i];
        if (t < D) {
            float bi = b_ih[t] + b_hh[t];
            float bg = b_ih[2 * D + t] + b_hh[2 * D + t];
            float bo = b_ih[3 * D + t] + b_hh[3 * D + t];
            float c = sigmoidf_(bi) * tanhf(bg);
            c1[t] = c;
            h1[t] = sigmoidf_(bo) * tanhf(c);
        }
    }
}

// ---------------- shared online-softmax update for 8 rows ----------------
__device__ __forceinline__ void online8(const float (&xf0)[8], const float (&xf1)[8],
                                        const float4 q0, const float4 q1,
                                        int base, int wer, int qg,
                                        float& m, float& s, float (&acc)[8]) {
    float p0 = xf0[0] * q0.x + xf0[1] * q0.y + xf0[2] * q0.z + xf0[3] * q0.w
             + xf0[4] * q1.x + xf0[5] * q1.y + xf0[6] * q1.z + xf0[7] * q1.w;
    float p1 = xf1[0] * q0.x + xf1[1] * q0.y + xf1[2] * q0.z + xf1[3] * q0.w
             + xf1[4] * q1.x + xf1[5] * q1.y + xf1[6] * q1.z + xf1[7] * q1.w;
#pragma unroll
    for (int off = 1; off < 16; off <<= 1) {
        p0 += __shfl_xor(p0, off);
        p1 += __shfl_xor(p1, off);
    }
    float p0a = __shfl_xor(p0, 16), p0b = __shfl_xor(p0, 32), p0c = __shfl_xor(p0a, 32);
    float p1a = __shfl_xor(p1, 16), p1b = __shfl_xor(p1, 32), p1c = __shfl_xor(p1a, 32);
    float s00 = (base + qg       < wer) ? p0  : -INFINITY;
    float s01 = (base + (qg ^ 1) < wer) ? p0a : -INFINITY;
    float s02 = (base + (qg ^ 2) < wer) ? p0b : -INFINITY;
    float s03 = (base + (qg ^ 3) < wer) ? p0c : -INFINITY;
    float s10 = (base + 4 + qg       < wer) ? p1  : -INFINITY;
    float s11 = (base + 4 + (qg ^ 1) < wer) ? p1a : -INFINITY;
    float s12 = (base + 4 + (qg ^ 2) < wer) ? p1b : -INFINITY;
    float s13 = (base + 4 + (qg ^ 3) < wer) ? p1c : -INFINITY;

    float mn = fmaxf(fmaxf(fmaxf(s00, s01), fmaxf(s02, s03)),
                     fmaxf(fmaxf(s10, s11), fmaxf(s12, s13)));
    mn = fmaxf(m, mn);
    float al = __expf(m - mn);
    float w00 = __expf(s00 - mn), w01 = __expf(s01 - mn);
    float w02 = __expf(s02 - mn), w03 = __expf(s03 - mn);
    float w10 = __expf(s10 - mn), w11 = __expf(s11 - mn);
    float w12 = __expf(s12 - mn), w13 = __expf(s13 - mn);
    float sg = (w00 + w01) + (w02 + w03) + ((w10 + w11) + (w12 + w13));
    s = s * al + sg;
#pragma unroll
    for (int j = 0; j < 8; ++j)
        acc[j] = acc[j] * al + w00 * xf0[j] + w10 * xf1[j];
    m = mn;
}

// merge 4 lane-groups intra-wave, then stash (m,s,acc-row) in LDS for the 2-wave combine
__device__ __forceinline__ void attn_store(float (&acc)[8], float m, float s,
                                           int seg, int half, int lane, int qg, int c,
                                           float (*gp)[4][512],
                                           float (*sm2)[2], float (*ss2)[2]) {
#pragma unroll
    for (int j = 0; j < 8; ++j) {
        acc[j] += __shfl_xor(acc[j], 16);
        acc[j] += __shfl_xor(acc[j], 32);
    }
    if (qg == 0) {
#pragma unroll
        for (int j = 0; j < 8; ++j) gp[half][seg][8 * c + j] = acc[j];
    }
    if (lane == 0) { sm2[seg][half] = m; ss2[seg][half] = s; }
}

// step-1 attention: fp32 x (nontemporal), emits fp16 copy
__device__ __forceinline__ void attn_pass_f32(const float* __restrict__ x,
                                              __half* __restrict__ xh,
                                              int ws, int we, int seg, int half,
                                              int lane, int qg, int c, const float* qrow,
                                              float (*gp)[4][512],
                                              float (*sm2)[2], float (*ss2)[2]) {
    float4 q0 = *(const float4*)&qrow[8 * c];
    float4 q1 = *(const float4*)&qrow[8 * c + 4];
    float m = -INFINITY, s = 0.f;
    float acc[8] = {0.f, 0.f, 0.f, 0.f, 0.f, 0.f, 0.f, 0.f};
    const f4v* x4 = (const f4v*)x;     // 32 per fp32 row
    float4* xh4 = (float4*)xh;         // 16 per fp16 row
    if (ws < we) {
        int last = we - 1;
        for (int base = ws; base < we; base += 8) {
            int r0 = min(base + qg, last);
            int r1 = min(base + 4 + qg, last);
            f4v f00 = __builtin_nontemporal_load(&x4[(size_t)r0 * 32 + 2 * c]);
            f4v f01 = __builtin_nontemporal_load(&x4[(size_t)r0 * 32 + 2 * c + 1]);
            f4v f10 = __builtin_nontemporal_load(&x4[(size_t)r1 * 32 + 2 * c]);
            f4v f11 = __builtin_nontemporal_load(&x4[(size_t)r1 * 32 + 2 * c + 1]);
            float xf0[8] = {f00.x, f00.y, f00.z, f00.w, f01.x, f01.y, f01.z, f01.w};
            float xf1[8] = {f10.x, f10.y, f10.z, f10.w, f11.x, f11.y, f11.z, f11.w};
            xh4[(size_t)r0 * 16 + c] = pack8_to_half8(xf0);
            xh4[(size_t)r1 * 16 + c] = pack8_to_half8(xf1);
            online8(xf0, xf1, q0, q1, base, we, qg, m, s, acc);
        }
    }
    attn_store(acc, m, s, seg, half, lane, qg, c, gp, sm2, ss2);
}

// steps-2,3 attention: fp16 x with register double-buffer prefetch
__device__ __forceinline__ void attn_pass_f16(const __half* __restrict__ xh,
                                              int ws, int we, int seg, int half,
                                              int lane, int qg, int c, const float* qrow,
                                              float (*gp)[4][512],
                                              float (*sm2)[2], float (*ss2)[2]) {
    float4 q0 = *(const float4*)&qrow[8 * c];
    float4 q1 = *(const float4*)&qrow[8 * c + 4];
    float m = -INFINITY, s = 0.f;
    float acc[8] = {0.f, 0.f, 0.f, 0.f, 0.f, 0.f, 0.f, 0.f};
    const float4* x4 = (const float4*)xh;  // 16 per fp16 row
    if (ws < we) {
        int last = we - 1;
        int r0 = min(ws + qg, last), r1 = min(ws + 4 + qg, last);
        float4 v0 = x4[(size_t)r0 * 16 + c];
        float4 v1 = x4[(size_t)r1 * 16 + c];
        for (int base = ws; base < we; ) {
            float4 cv0 = v0, cv1 = v1;
            int nb = base + 8;
            if (nb < we) {                       // prefetch next iteration's rows
                int n0 = min(nb + qg, last), n1 = min(nb + 4 + qg, last);
                v0 = x4[(size_t)n0 * 16 + c];
                v1 = x4[(size_t)n1 * 16 + c];
            }
            const __half2* h0 = (const __half2*)&cv0;
            const __half2* h1 = (const __half2*)&cv1;
            float2 a0 = __half22float2(h0[0]), a1 = __half22float2(h0[1]);
            float2 a2 = __half22float2(h0[2]), a3 = __half22float2(h0[3]);
            float2 b0 = __half22float2(h1[0]), b1 = __half22float2(h1[1]);
            float2 b2 = __half22float2(h1[2]), b3 = __half22float2(h1[3]);
            float xf0[8] = {a0.x, a0.y, a1.x, a1.y, a2.x, a2.y, a3.x, a3.y};
            float xf1[8] = {b0.x, b0.y, b1.x, b1.y, b2.x, b2.y, b3.x, b3.y};
            online8(xf0, xf1, q0, q1, base, we, qg, m, s, acc);
            base = nb;
        }
    }
    attn_store(acc, m, s, seg, half, lane, qg, c, gp, sm2, ss2);
}

// combine the 2 half-waves' online-softmax states; 512 threads cover 4 segs x 128 cols
__device__ __forceinline__ void attn_combine(const float (*gp)[4][512],
                                             const float (*sm2)[2], const float (*ss2)[2],
                                             float (*qs)[256], float* __restrict__ out,
                                             int gbase, int G, bool final_step) {
    int tid = threadIdx.x;
    int s2 = tid >> 7, col = tid & 127;
    float m0 = sm2[s2][0], m1 = sm2[s2][1];
    float mstar = fmaxf(m0, m1);
    float r = 0.f;
    if (mstar > -INFINITY) {
        float e0 = __expf(m0 - mstar), e1 = __expf(m1 - mstar);
        float stot = ss2[s2][0] * e0 + ss2[s2][1] * e1;
        float at = gp[0][s2][col] * e0 + gp[1][s2][col] * e1;
        r = at / fmaxf(stot, 1e-16f);
    }
    if (!final_step) qs[s2][128 + col] = r;
    else if (gbase + s2 < G) out[(size_t)(gbase + s2) * 256 + 128 + col] = r;
}

// ---------------- monolithic per-segment kernel ----------------
// Block = 512 threads = 8 waves = 4 segments; waves s and s+4 split segment s's rows.
// All state (h,c,r,gates) in LDS; weights stream from L2 (WcatT, 512 KB, shared).
__global__ __launch_bounds__(512, 8) void fused_kernel(
    const float* __restrict__ x, __half* __restrict__ xh,
    const int* __restrict__ seg_off, const float* __restrict__ WcatT,
    const float* __restrict__ b_sum, const float* __restrict__ h1,
    const float* __restrict__ c1, float* __restrict__ out, int G) {

    __shared__ float qs[4][256];       // per segment: [h(128) | r(128)]
    __shared__ float cL[4][128];       // cell state
    __shared__ float gp[2][4][512];    // matvec k-partials / attn combine scratch
    __shared__ float bL[512];          // bias
    __shared__ float sm2[4][2], ss2[4][2];

    int tid = threadIdx.x;
    int w = tid >> 6, lane = tid & 63;
    int qg = lane >> 4, c = lane & 15;
    int seg = w & 3, half = w >> 2;
    int gbase = blockIdx.x * 4;
    int g = gbase + seg;
    int ws = 0, we = 0;
    if (g < G) {
        int st = seg_off[g], en = seg_off[g + 1];
        int cnt = en - st;
        int chunk = (cnt + 1) >> 1;
        ws = st + half * chunk;
        we = min(ws + chunk, en);
    }

    bL[tid & 511] = b_sum[tid & 511];
    {
        int s2 = tid >> 7, k = tid & 127;
        qs[s2][k] = h1[k];
        cL[s2][k] = c1[k];
    }
    __syncthreads();

    // matvec roles: tl = tid&255 -> gate-col pair j0 = 2*tl; kh = tid>>8 -> k half
    int tl = tid & 255, kh = tid >> 8;
    int j0 = 2 * tl;
    int koff = kh * 128;
    const float* wp = WcatT + (size_t)koff * 512 + j0;

    // ======== step 1: attention (fp32 x -> fp16 emit), q = h1 ========
    attn_pass_f32(x, xh, ws, we, seg, half, lane, qg, c, &qs[seg][0], gp, sm2, ss2);
    __syncthreads();
    attn_combine(gp, sm2, ss2, qs, out, gbase, G, false);
    __syncthreads();

#pragma unroll 1
    for (int step = 0; step < 2; ++step) {
        bool final_step = (step == 1);
        // ---- matvec (k-split): gp[kh][s][j] = sum_{k in half} WcatT[k][j]*qs[s][k] ----
        float a0[4] = {0.f, 0.f, 0.f, 0.f};
        float a1[4] = {0.f, 0.f, 0.f, 0.f};
        for (int k = 0; k < 128; k += 4) {
            float qv[4][4];
            *(float4*)qv[0] = *(const float4*)&qs[0][koff + k];
            *(float4*)qv[1] = *(const float4*)&qs[1][koff + k];
            *(float4*)qv[2] = *(const float4*)&qs[2][koff + k];
            *(float4*)qv[3] = *(const float4*)&qs[3][koff + k];
#pragma unroll
            for (int dk = 0; dk < 4; ++dk) {
                float2 wv = *(const float2*)&wp[(size_t)(k + dk) * 512];
#pragma unroll
                for (int s2 = 0; s2 < 4; ++s2) {
                    a0[s2] = fmaf(qv[s2][dk], wv.x, a0[s2]);
                    a1[s2] = fmaf(qv[s2][dk], wv.y, a1[s2]);
                }
            }
        }
#pragma unroll
        for (int s2 = 0; s2 < 4; ++s2) {
            float2 o; o.x = a0[s2]; o.y = a1[s2];
            *(float2*)&gp[kh][s2][j0] = o;
        }
        __syncthreads();

        // ---- LSTM cell: combine k-partials + bias, 512 threads = 4 segs x 128 ----
        {
            int s2 = tid >> 7, k = tid & 127;
            float ig = gp[0][s2][k]       + gp[1][s2][k]       + bL[k];
            float fg = gp[0][s2][128 + k] + gp[1][s2][128 + k] + bL[128 + k];
            float gg = gp[0][s2][256 + k] + gp[1][s2][256 + k] + bL[256 + k];
            float og = gp[0][s2][384 + k] + gp[1][s2][384 + k] + bL[384 + k];
            float cp = cL[s2][k];
            float cc = sigmoidf_(fg) * cp + sigmoidf_(ig) * tanhf(gg);
            float hh = sigmoidf_(og) * tanhf(cc);
            cL[s2][k] = cc;
            qs[s2][k] = hh;
            if (final_step && (gbase + s2) < G)
                out[(size_t)(gbase + s2) * 256 + k] = hh;   // h3 -> out[:, :128]
        }
        __syncthreads();

        // ---- attention with q = new h ----
        attn_pass_f16(xh, ws, we, seg, half, lane, qg, c, &qs[seg][0], gp, sm2, ss2);
        __syncthreads();
        attn_combine(gp, sm2, ss2, qs, out, gbase, G, final_step);
        __syncthreads();
    }
}

extern "C" void kernel_launch(void* const* d_in, const int* in_sizes, int n_in,
                              void* d_out, int out_size, void* d_ws, size_t ws_size,
                              hipStream_t stream) {
    const float* x      = (const float*)d_in[0];
    const float* W_ih   = (const float*)d_in[1];
    const float* W_hh   = (const float*)d_in[2];
    const float* b_ih   = (const float*)d_in[3];
    const float* b_hh   = (const float*)d_in[4];
    const int*   index  = (const int*)d_in[5];
    int N = in_sizes[5];
    int G = out_size / (2 * D);
    float* out = (float*)d_out;
    size_t totalx = (size_t)N * D;

    float* ws = (float*)d_ws;
    __half* xh    = (__half*)ws;                        // N*D halfs
    float* WcatT  = ws + totalx / 2;                    // 256*512
    float* b_sum  = WcatT + 256 * 512;                  // 512
    float* h1     = b_sum + 4 * D;                      // 128
    float* c1     = h1 + D;                             // 128
    int* seg_off  = (int*)(c1 + D);                     // G+1

    prep_kernel<<<274, 256, 0, stream>>>(W_ih, W_hh, b_ih, b_hh, index, N, G,
                                         WcatT, seg_off, b_sum, h1, c1);

    int nb = (G + 3) >> 2;
    fused_kernel<<<nb, 512, 0, stream>>>(x, xh, seg_off, WcatT, b_sum, h1, c1, out, G);
}

// Round 5
// 930.048 us; speedup vs baseline: 1.0887x; 1.0887x over previous
//
#include <hip/hip_runtime.h>
#include <hip/hip_fp16.h>
#include <math.h>

#define D 128

typedef float f4v __attribute__((ext_vector_type(4)));

__device__ __forceinline__ float sigmoidf_(float x) { return 1.f / (1.f + __expf(-x)); }

__device__ __forceinline__ float4 pack8_to_half8(const float* xf) {
    __half2 hh[4];
    hh[0] = __floats2half2_rn(xf[0], xf[1]);
    hh[1] = __floats2half2_rn(xf[2], xf[3]);
    hh[2] = __floats2half2_rn(xf[4], xf[5]);
    hh[3] = __floats2half2_rn(xf[6], xf[7]);
    return *(float4*)hh;
}

// ---------------- prep: WcatT | seg_off | b_sum,h1,c1 ----------------
// WcatT[k][j] (k<256 input dim, j<512 gate rows), layout [256][512]:
//   k<128 : W_ih[j][k] + W_hh[j][k]   (h part)
//   k>=128: W_ih[j][k]                (r part)
__global__ void prep_kernel(const float* __restrict__ W_ih, const float* __restrict__ W_hh,
                            const float* __restrict__ b_ih, const float* __restrict__ b_hh,
                            const int* __restrict__ idx, int N, int G,
                            float* __restrict__ WcatT, int* __restrict__ seg_off,
                            float* __restrict__ b_sum, float* __restrict__ h1,
                            float* __restrict__ c1) {
    int b = blockIdx.x, t = threadIdx.x;
    if (b < 256) {
        int k = b;
        for (int j = t; j < 512; j += 256) {
            float v = W_ih[(size_t)j * 256 + k];
            if (k < 128) v += W_hh[(size_t)j * 128 + k];
            WcatT[(size_t)k * 512 + j] = v;
        }
    } else if (b < 273) {
        int g = (b - 256) * 256 + t;
        if (g <= G) {
            int lo = 0, hi = N;
            while (lo < hi) {
                int mid = (lo + hi) >> 1;
                if (idx[mid] < g) lo = mid + 1; else hi = mid;
            }
            seg_off[g] = lo;
        }
    } else {
        for (int i = t; i < 4 * D; i += 256) b_sum[i] = b_ih[i] + b_hh[i];
        if (t < D) {
            float bi = b_ih[t] + b_hh[t];
            float bg = b_ih[2 * D + t] + b_hh[2 * D + t];
            float bo = b_ih[3 * D + t] + b_hh[3 * D + t];
            float c = sigmoidf_(bi) * tanhf(bg);
            c1[t] = c;
            h1[t] = sigmoidf_(bo) * tanhf(c);
        }
    }
}

// ---------------- shared online-softmax update for 8 rows ----------------
__device__ __forceinline__ void online8(const float (&xf0)[8], const float (&xf1)[8],
                                        const float4 q0, const float4 q1,
                                        int base, int wer, int qg,
                                        float& m, float& s, float (&acc)[8]) {
    float p0 = xf0[0] * q0.x + xf0[1] * q0.y + xf0[2] * q0.z + xf0[3] * q0.w
             + xf0[4] * q1.x + xf0[5] * q1.y + xf0[6] * q1.z + xf0[7] * q1.w;
    float p1 = xf1[0] * q0.x + xf1[1] * q0.y + xf1[2] * q0.z + xf1[3] * q0.w
             + xf1[4] * q1.x + xf1[5] * q1.y + xf1[6] * q1.z + xf1[7] * q1.w;
#pragma unroll
    for (int off = 1; off < 16; off <<= 1) {
        p0 += __shfl_xor(p0, off);
        p1 += __shfl_xor(p1, off);
    }
    float p0a = __shfl_xor(p0, 16), p0b = __shfl_xor(p0, 32), p0c = __shfl_xor(p0a, 32);
    float p1a = __shfl_xor(p1, 16), p1b = __shfl_xor(p1, 32), p1c = __shfl_xor(p1a, 32);
    float s00 = (base + qg       < wer) ? p0  : -INFINITY;
    float s01 = (base + (qg ^ 1) < wer) ? p0a : -INFINITY;
    float s02 = (base + (qg ^ 2) < wer) ? p0b : -INFINITY;
    float s03 = (base + (qg ^ 3) < wer) ? p0c : -INFINITY;
    float s10 = (base + 4 + qg       < wer) ? p1  : -INFINITY;
    float s11 = (base + 4 + (qg ^ 1) < wer) ? p1a : -INFINITY;
    float s12 = (base + 4 + (qg ^ 2) < wer) ? p1b : -INFINITY;
    float s13 = (base + 4 + (qg ^ 3) < wer) ? p1c : -INFINITY;

    float mn = fmaxf(fmaxf(fmaxf(s00, s01), fmaxf(s02, s03)),
                     fmaxf(fmaxf(s10, s11), fmaxf(s12, s13)));
    mn = fmaxf(m, mn);
    float al = __expf(m - mn);
    float w00 = __expf(s00 - mn), w01 = __expf(s01 - mn);
    float w02 = __expf(s02 - mn), w03 = __expf(s03 - mn);
    float w10 = __expf(s10 - mn), w11 = __expf(s11 - mn);
    float w12 = __expf(s12 - mn), w13 = __expf(s13 - mn);
    float sg = (w00 + w01) + (w02 + w03) + ((w10 + w11) + (w12 + w13));
    s = s * al + sg;
#pragma unroll
    for (int j = 0; j < 8; ++j)
        acc[j] = acc[j] * al + w00 * xf0[j] + w10 * xf1[j];
    m = mn;
}

// merge 4 lane-groups intra-wave, then stash (m,s,acc-row) in LDS for the 2-wave combine
__device__ __forceinline__ void attn_store(float (&acc)[8], float m, float s,
                                           int seg, int half, int lane, int qg, int c,
                                           float (*gp)[4][512],
                                           float (*sm2)[2], float (*ss2)[2]) {
#pragma unroll
    for (int j = 0; j < 8; ++j) {
        acc[j] += __shfl_xor(acc[j], 16);
        acc[j] += __shfl_xor(acc[j], 32);
    }
    if (qg == 0) {
#pragma unroll
        for (int j = 0; j < 8; ++j) gp[half][seg][8 * c + j] = acc[j];
    }
    if (lane == 0) { sm2[seg][half] = m; ss2[seg][half] = s; }
}

// step-1 attention: fp32 x (nontemporal), emits fp16 copy
__device__ __forceinline__ void attn_pass_f32(const float* __restrict__ x,
                                              __half* __restrict__ xh,
                                              int ws, int we, int seg, int half,
                                              int lane, int qg, int c, const float* qrow,
                                              float (*gp)[4][512],
                                              float (*sm2)[2], float (*ss2)[2]) {
    float4 q0 = *(const float4*)&qrow[8 * c];
    float4 q1 = *(const float4*)&qrow[8 * c + 4];
    float m = -INFINITY, s = 0.f;
    float acc[8] = {0.f, 0.f, 0.f, 0.f, 0.f, 0.f, 0.f, 0.f};
    const f4v* x4 = (const f4v*)x;     // 32 per fp32 row
    float4* xh4 = (float4*)xh;         // 16 per fp16 row
    if (ws < we) {
        int last = we - 1;
        for (int base = ws; base < we; base += 8) {
            int r0 = min(base + qg, last);
            int r1 = min(base + 4 + qg, last);
            f4v f00 = __builtin_nontemporal_load(&x4[(size_t)r0 * 32 + 2 * c]);
            f4v f01 = __builtin_nontemporal_load(&x4[(size_t)r0 * 32 + 2 * c + 1]);
            f4v f10 = __builtin_nontemporal_load(&x4[(size_t)r1 * 32 + 2 * c]);
            f4v f11 = __builtin_nontemporal_load(&x4[(size_t)r1 * 32 + 2 * c + 1]);
            float xf0[8] = {f00.x, f00.y, f00.z, f00.w, f01.x, f01.y, f01.z, f01.w};
            float xf1[8] = {f10.x, f10.y, f10.z, f10.w, f11.x, f11.y, f11.z, f11.w};
            xh4[(size_t)r0 * 16 + c] = pack8_to_half8(xf0);
            xh4[(size_t)r1 * 16 + c] = pack8_to_half8(xf1);
            online8(xf0, xf1, q0, q1, base, we, qg, m, s, acc);
        }
    }
    attn_store(acc, m, s, seg, half, lane, qg, c, gp, sm2, ss2);
}

// steps-2,3 attention: fp16 x with register double-buffer prefetch
__device__ __forceinline__ void attn_pass_f16(const __half* __restrict__ xh,
                                              int ws, int we, int seg, int half,
                                              int lane, int qg, int c, const float* qrow,
                                              float (*gp)[4][512],
                                              float (*sm2)[2], float (*ss2)[2]) {
    float4 q0 = *(const float4*)&qrow[8 * c];
    float4 q1 = *(const float4*)&qrow[8 * c + 4];
    float m = -INFINITY, s = 0.f;
    float acc[8] = {0.f, 0.f, 0.f, 0.f, 0.f, 0.f, 0.f, 0.f};
    const float4* x4 = (const float4*)xh;  // 16 per fp16 row
    if (ws < we) {
        int last = we - 1;
        int r0 = min(ws + qg, last), r1 = min(ws + 4 + qg, last);
        float4 v0 = x4[(size_t)r0 * 16 + c];
        float4 v1 = x4[(size_t)r1 * 16 + c];
        for (int base = ws; base < we; ) {
            float4 cv0 = v0, cv1 = v1;
            int nb = base + 8;
            if (nb < we) {                       // prefetch next iteration's rows
                int n0 = min(nb + qg, last), n1 = min(nb + 4 + qg, last);
                v0 = x4[(size_t)n0 * 16 + c];
                v1 = x4[(size_t)n1 * 16 + c];
            }
            const __half2* h0 = (const __half2*)&cv0;
            const __half2* h1 = (const __half2*)&cv1;
            float2 a0 = __half22float2(h0[0]), a1 = __half22float2(h0[1]);
            float2 a2 = __half22float2(h0[2]), a3 = __half22float2(h0[3]);
            float2 b0 = __half22float2(h1[0]), b1 = __half22float2(h1[1]);
            float2 b2 = __half22float2(h1[2]), b3 = __half22float2(h1[3]);
            float xf0[8] = {a0.x, a0.y, a1.x, a1.y, a2.x, a2.y, a3.x, a3.y};
            float xf1[8] = {b0.x, b0.y, b1.x, b1.y, b2.x, b2.y, b3.x, b3.y};
            online8(xf0, xf1, q0, q1, base, we, qg, m, s, acc);
            base = nb;
        }
    }
    attn_store(acc, m, s, seg, half, lane, qg, c, gp, sm2, ss2);
}

// combine the 2 half-waves' online-softmax states; 512 threads cover 4 segs x 128 cols
__device__ __forceinline__ void attn_combine(const float (*gp)[4][512],
                                             const float (*sm2)[2], const float (*ss2)[2],
                                             float (*qs)[256], float* __restrict__ out,
                                             int gbase, int G, bool final_step) {
    int tid = threadIdx.x;
    int s2 = tid >> 7, col = tid & 127;
    float m0 = sm2[s2][0], m1 = sm2[s2][1];
    float mstar = fmaxf(m0, m1);
    float r = 0.f;
    if (mstar > -INFINITY) {
        float e0 = __expf(m0 - mstar), e1 = __expf(m1 - mstar);
        float stot = ss2[s2][0] * e0 + ss2[s2][1] * e1;
        float at = gp[0][s2][col] * e0 + gp[1][s2][col] * e1;
        r = at / fmaxf(stot, 1e-16f);
    }
    if (!final_step) qs[s2][128 + col] = r;
    else if (gbase + s2 < G) out[(size_t)(gbase + s2) * 256 + 128 + col] = r;
}

// ---------------- monolithic per-segment kernel ----------------
// Block = 512 threads = 8 waves = 4 segments; waves s and s+4 split segment s's rows.
// All state (h,c,r,gates) in LDS; weights stream from L2 (WcatT, 512 KB, shared).
// launch_bounds(512, 4): VGPR cap 128 — (512,8) forced 32 VGPR and spilled ~1.7 GB of
// scratch traffic to HBM (round-4 post-mortem). Grid (4 blk/CU) is the occupancy limit.
__global__ __launch_bounds__(512, 4) void fused_kernel(
    const float* __restrict__ x, __half* __restrict__ xh,
    const int* __restrict__ seg_off, const float* __restrict__ WcatT,
    const float* __restrict__ b_sum, const float* __restrict__ h1,
    const float* __restrict__ c1, float* __restrict__ out, int G) {

    __shared__ float qs[4][256];       // per segment: [h(128) | r(128)]
    __shared__ float cL[4][128];       // cell state
    __shared__ float gp[2][4][512];    // matvec k-partials / attn combine scratch
    __shared__ float bL[512];          // bias
    __shared__ float sm2[4][2], ss2[4][2];

    int tid = threadIdx.x;
    int w = tid >> 6, lane = tid & 63;
    int qg = lane >> 4, c = lane & 15;
    int seg = w & 3, half = w >> 2;
    int gbase = blockIdx.x * 4;
    int g = gbase + seg;
    int ws = 0, we = 0;
    if (g < G) {
        int st = seg_off[g], en = seg_off[g + 1];
        int cnt = en - st;
        int chunk = (cnt + 1) >> 1;
        ws = st + half * chunk;
        we = min(ws + chunk, en);
    }

    bL[tid & 511] = b_sum[tid & 511];
    {
        int s2 = tid >> 7, k = tid & 127;
        qs[s2][k] = h1[k];
        cL[s2][k] = c1[k];
    }
    __syncthreads();

    // matvec roles: tl = tid&255 -> gate-col pair j0 = 2*tl; kh = tid>>8 -> k half
    int tl = tid & 255, kh = tid >> 8;
    int j0 = 2 * tl;
    int koff = kh * 128;
    const float* wp = WcatT + (size_t)koff * 512 + j0;

    // ======== step 1: attention (fp32 x -> fp16 emit), q = h1 ========
    attn_pass_f32(x, xh, ws, we, seg, half, lane, qg, c, &qs[seg][0], gp, sm2, ss2);
    __syncthreads();
    attn_combine(gp, sm2, ss2, qs, out, gbase, G, false);
    __syncthreads();

#pragma unroll 1
    for (int step = 0; step < 2; ++step) {
        bool final_step = (step == 1);
        // ---- matvec (k-split): gp[kh][s][j] = sum_{k in half} WcatT[k][j]*qs[s][k] ----
        float a0[4] = {0.f, 0.f, 0.f, 0.f};
        float a1[4] = {0.f, 0.f, 0.f, 0.f};
        for (int k = 0; k < 128; k += 4) {
            float qv[4][4];
            *(float4*)qv[0] = *(const float4*)&qs[0][koff + k];
            *(float4*)qv[1] = *(const float4*)&qs[1][koff + k];
            *(float4*)qv[2] = *(const float4*)&qs[2][koff + k];
            *(float4*)qv[3] = *(const float4*)&qs[3][koff + k];
#pragma unroll
            for (int dk = 0; dk < 4; ++dk) {
                float2 wv = *(const float2*)&wp[(size_t)(k + dk) * 512];
#pragma unroll
                for (int s2 = 0; s2 < 4; ++s2) {
                    a0[s2] = fmaf(qv[s2][dk], wv.x, a0[s2]);
                    a1[s2] = fmaf(qv[s2][dk], wv.y, a1[s2]);
                }
            }
        }
#pragma unroll
        for (int s2 = 0; s2 < 4; ++s2) {
            float2 o; o.x = a0[s2]; o.y = a1[s2];
            *(float2*)&gp[kh][s2][j0] = o;
        }
        __syncthreads();

        // ---- LSTM cell: combine k-partials + bias, 512 threads = 4 segs x 128 ----
        {
            int s2 = tid >> 7, k = tid & 127;
            float ig = gp[0][s2][k]       + gp[1][s2][k]       + bL[k];
            float fg = gp[0][s2][128 + k] + gp[1][s2][128 + k] + bL[128 + k];
            float gg = gp[0][s2][256 + k] + gp[1][s2][256 + k] + bL[256 + k];
            float og = gp[0][s2][384 + k] + gp[1][s2][384 + k] + bL[384 + k];
            float cp = cL[s2][k];
            float cc = sigmoidf_(fg) * cp + sigmoidf_(ig) * tanhf(gg);
            float hh = sigmoidf_(og) * tanhf(cc);
            cL[s2][k] = cc;
            qs[s2][k] = hh;
            if (final_step && (gbase + s2) < G)
                out[(size_t)(gbase + s2) * 256 + k] = hh;   // h3 -> out[:, :128]
        }
        __syncthreads();

        // ---- attention with q = new h ----
        attn_pass_f16(xh, ws, we, seg, half, lane, qg, c, &qs[seg][0], gp, sm2, ss2);
        __syncthreads();
        attn_combine(gp, sm2, ss2, qs, out, gbase, G, final_step);
        __syncthreads();
    }
}

extern "C" void kernel_launch(void* const* d_in, const int* in_sizes, int n_in,
                              void* d_out, int out_size, void* d_ws, size_t ws_size,
                              hipStream_t stream) {
    const float* x      = (const float*)d_in[0];
    const float* W_ih   = (const float*)d_in[1];
    const float* W_hh   = (const float*)d_in[2];
    const float* b_ih   = (const float*)d_in[3];
    const float* b_hh   = (const float*)d_in[4];
    const int*   index  = (const int*)d_in[5];
    int N = in_sizes[5];
    int G = out_size / (2 * D);
    float* out = (float*)d_out;
    size_t totalx = (size_t)N * D;

    float* ws = (float*)d_ws;
    __half* xh    = (__half*)ws;                        // N*D halfs
    float* WcatT  = ws + totalx / 2;                    // 256*512
    float* b_sum  = WcatT + 256 * 512;                  // 512
    float* h1     = b_sum + 4 * D;                      // 128
    float* c1     = h1 + D;                             // 128
    int* seg_off  = (int*)(c1 + D);                     // G+1

    prep_kernel<<<274, 256, 0, stream>>>(W_ih, W_hh, b_ih, b_hh, index, N, G,
                                         WcatT, seg_off, b_sum, h1, c1);

    int nb = (G + 3) >> 2;
    fused_kernel<<<nb, 512, 0, stream>>>(x, xh, seg_off, WcatT, b_sum, h1, c1, out, G);
}